// Round 3
// baseline (433.982 us; speedup 1.0000x reference)
//
#include <hip/hip_runtime.h>
#include <hip/hip_bf16.h>

// ---------------- ArcFace constants ----------------
#define ARC_S    30.0f
#define ARC_COSM 0.8775825618903728f   // cos(0.5)
#define ARC_SINM 0.4794255386042030f   // sin(0.5)
#define ARC_TH  -0.8775825618903728f   // cos(pi-0.5)
#define ARC_MM   0.2397127693021015f   // sin(pi-0.5)*0.5

#define B_ROWS 512
#define D_DIM  512
#define C_CLS  100000
#define C_PAD  100096                  // 391 * 256

typedef float  floatx4 __attribute__((ext_vector_type(4)));
typedef __bf16 bf16x8  __attribute__((ext_vector_type(8)));

// ---------------------------------------------------------------------------
// Row L2-normalize (row length fixed = 512 floats) -> bf16.
// One wave per row; 4 rows per 256-thread block. Rows >= valid_rows get zeros.
// ---------------------------------------------------------------------------
__global__ __launch_bounds__(256) void normalize_rows_512(
    const float* __restrict__ src, __bf16* __restrict__ dst, int valid_rows)
{
    const int lane = threadIdx.x & 63;
    const int wave = threadIdx.x >> 6;
    const long long row = (long long)blockIdx.x * 4 + wave;

    __bf16* drow = dst + row * D_DIM;

    if (row >= valid_rows) {
        bf16x8 z;
        #pragma unroll
        for (int i = 0; i < 8; i++) z[i] = (__bf16)0.0f;
        *(bf16x8*)(drow + lane * 8) = z;
        return;
    }

    const float4* rp = (const float4*)(src + row * D_DIM);
    float4 p0 = rp[lane * 2];
    float4 p1 = rp[lane * 2 + 1];

    float ss = p0.x*p0.x + p0.y*p0.y + p0.z*p0.z + p0.w*p0.w
             + p1.x*p1.x + p1.y*p1.y + p1.z*p1.z + p1.w*p1.w;
    #pragma unroll
    for (int m = 32; m >= 1; m >>= 1) ss += __shfl_xor(ss, m, 64);

    const float scale = 1.0f / fmaxf(sqrtf(ss), 1e-12f);

    bf16x8 v;
    v[0] = (__bf16)(p0.x * scale);
    v[1] = (__bf16)(p0.y * scale);
    v[2] = (__bf16)(p0.z * scale);
    v[3] = (__bf16)(p0.w * scale);
    v[4] = (__bf16)(p1.x * scale);
    v[5] = (__bf16)(p1.y * scale);
    v[6] = (__bf16)(p1.z * scale);
    v[7] = (__bf16)(p1.w * scale);
    *(bf16x8*)(drow + lane * 8) = v;
}

// ---------------------------------------------------------------------------
// v4: 8-phase 256x256 template (m201 port).  M=512,N=100096,K=512 bf16 MFMA
// + fused ArcFace epilogue.
//
// 256x256 tile, BK=64, 512 thr = 8 waves (2M x 4N).  Wave output 128x64 via
// INTERLEAVED chunks: rows wr*64 + mh*128 + mi*16, cols wc*32 + nh*128 +
// nj*16 -> phase quadrant q: (mh,nh) = 00,01,11,10 touches exactly A-half
// (q>>1) and B-half (q==0||q==3 ? 0 : 1).  32 phases = 8 K-tiles x 4.
//
// Per phase: ds_read quadrant frags (12/4/8/0 by q: b0 frags live in regs
// across the whole K-tile, halving LDS traffic so the DS pipe stays under
// the MFMA pipe) | stage ONE half-tile (2x global_load_lds 16B/thread) |
// raw s_barrier | lgkmcnt(0) | setprio(1) 16 MFMA setprio(0) | raw barrier.
// vmcnt(8) ONCE per K-tile (4 half-tiles = 8 loads stay in flight; staged
// half-tiles have 4-7 phases of latency cover).  Stage stream for K-tile k:
// [A0@4k-7, B0@4k-6, B1@4k-5, A1@4k-4] -- each region's last reader
// finished >=1 barrier earlier (audited per-quadrant).
//
// LDS 128KB double-buffered -> 1 block/CU; pipeline depth replaces TLP.
// XOR swizzle for BK=64 rows (8x16B chunks): slot kc holds gmem chunk
// kc^(row&7); wave read = 16 rows x (ks,fch) chunks -> uniform 8 dw/bank =
// conflict-free.  Achieved by pre-swizzling the GLOBAL source column
// (global_load_lds dest must stay linear).  Accumulation k-order identical
// to v3 (bit-identical numerics).  Output stores nontemporal (200MB stream
// must not evict the 102MB W set from L2/L3).
// ---------------------------------------------------------------------------
#define BM 256
#define BN 256
#define BK 64
#define KT 8            // K-tiles
#define N_TILES 391     // C_PAD / BN
#define GRID_B  784     // 16 * 49

#define WAITVM(N) asm volatile("s_waitcnt vmcnt(" #N ")" ::: "memory")
#define WAITLG0() asm volatile("s_waitcnt lgkmcnt(0)" ::: "memory")
#define BARRIER() asm volatile("s_barrier" ::: "memory")

__device__ inline void async_load_16B(__bf16* lds, const __bf16* gmem)
{
    __builtin_amdgcn_global_load_lds(
        (const __attribute__((address_space(1))) void*)gmem,
        (__attribute__((address_space(3))) void*)lds,
        16, 0, 0);
}

__global__ __launch_bounds__(512, 2) void gemm_arcface(
    const __bf16* __restrict__ A,
    const __bf16* __restrict__ W,
    const int*    __restrict__ label,
    float*        __restrict__ out)
{
    // XCD-aware swizzle: groups of 16 ids = 8 n-tiles x 2 m-tiles, m-pair
    // ids differ by 8 (same XCD under %8 round-robin) -> W panel L2 reuse.
    const int b  = blockIdx.x;
    const int nt = (b & 7) + 8 * (b >> 4);
    const int mt = (b >> 3) & 1;
    if (nt >= N_TILES) return;   // 2 idle blocks

    __shared__ __bf16 As[2][BM * BK];   // 2 x 32 KB
    __shared__ __bf16 Bs[2][BN * BK];   // 2 x 32 KB
    __shared__ int    sLab[BM];

    const int tid = threadIdx.x;
    const int m0  = mt * BM;
    const int n0  = nt * BN;

    if (tid < BM) sLab[tid] = label[m0 + tid];   // oldest vmem op, retired by 1st wait

    const int lane = tid & 63;
    const int wave = tid >> 6;
    const int wr   = wave >> 2;        // 0..1 (M)
    const int wc   = wave & 3;         // 0..3 (N)
    const int frow = lane & 15;
    const int fch  = lane >> 4;        // 0..3

    // ---- staging bases: thread handles 16B chunks j=tid and j=tid+512 ----
    // row-in-half = j>>3 (0..127), chunk slot = j&7, gmem col chunk =
    // (j&7)^(row&7).  (tid+512 is row+64: same &7 pattern.)
    const int lrow = tid >> 3;
    const int kcs  = (tid & 7) ^ (lrow & 7);
    const __bf16* pA0 = A + (long long)(m0 + lrow) * D_DIM + kcs * 8;
    const __bf16* pB0 = W + (long long)(n0 + lrow) * D_DIM + kcs * 8;
    const __bf16* pA1 = pA0 + 128 * D_DIM;
    const __bf16* pB1 = pB0 + 128 * D_DIM;

    // stage half h of K-tile k; stream order h: 0=A0, 1=B0, 2=B1, 3=A1
    #define STAGE(k, h) do {                                                  \
        const __bf16* _g = ((h) == 0 ? pA0 : (h) == 1 ? pB0 :                 \
                            (h) == 2 ? pB1 : pA1) + (k) * BK;                 \
        __bf16* _l = (((h) == 0 || (h) == 3) ? &As[(k) & 1][0]                \
                                             : &Bs[(k) & 1][0])               \
                     + (((h) >= 2) ? 128 * BK : 0);                           \
        async_load_16B(_l + tid * 8,         _g);                             \
        async_load_16B(_l + (tid + 512) * 8, _g + 64 * D_DIM);                \
    } while (0)

    // ---- ds_read lane offsets (within a 128-row half; elem units) ----
    int aoff[4][2], boff[2][2];
    #pragma unroll
    for (int ks = 0; ks < 2; ks++) {
        const int col = ((ks * 4 + fch) ^ (frow & 7)) * 8;
        #pragma unroll
        for (int mi = 0; mi < 4; mi++) aoff[mi][ks] = (mi * 16 + frow) * BK + col;
        #pragma unroll
        for (int nj = 0; nj < 2; nj++) boff[nj][ks] = (nj * 16 + frow) * BK + col;
    }
    const int aW = wr * 64 * BK;       // wave A-row base within a half
    const int bW = wc * 32 * BK;       // wave B-row base within a half

    floatx4 acc[2][4][2][2];
    #pragma unroll
    for (int mh = 0; mh < 2; mh++)
        #pragma unroll
        for (int mi = 0; mi < 4; mi++)
            #pragma unroll
            for (int nh = 0; nh < 2; nh++)
                #pragma unroll
                for (int nj = 0; nj < 2; nj++)
                    acc[mh][mi][nh][nj] = (floatx4)(0.0f);

    bf16x8 a[4][2], b0[2][2], b1[2][2];

    // ---- prologue: K-tiles 0 and 1 fully staged (16 loads/thread) ----
    STAGE(0, 0); STAGE(0, 1); STAGE(0, 2); STAGE(0, 3);
    STAGE(1, 0); STAGE(1, 1); STAGE(1, 2); STAGE(1, 3);

    // ---- 32-phase main loop ----
    #pragma unroll
    for (int p = 0; p < 4 * KT; ++p) {
        const int g = p >> 2;          // K-tile
        const int q = p & 3;           // quadrant: (mh,nh) = 00,01,11,10

        // stage stream element e = p-1 -> half (e&3) of K-tile 2+(e>>2)
        if (p >= 1 && p <= 24) { const int e = p - 1; STAGE(2 + (e >> 2), e & 3); }

        if (q == 0) {                  // once per K-tile: K-tile g landed,
            if (g < KT - 1) WAITVM(8); // 4 half-tiles (8 loads) stay in flight
            else            WAITVM(0);
        }
        BARRIER();

        const __bf16* as = &As[g & 1][0];
        const __bf16* bs = &Bs[g & 1][0];
        if (q == 0) {                  // a <- A-half0, b0 <- B-half0
            #pragma unroll
            for (int mi = 0; mi < 4; mi++)
                #pragma unroll
                for (int ks = 0; ks < 2; ks++)
                    a[mi][ks] = *(const bf16x8*)(as + aW + aoff[mi][ks]);
            #pragma unroll
            for (int nj = 0; nj < 2; nj++)
                #pragma unroll
                for (int ks = 0; ks < 2; ks++)
                    b0[nj][ks] = *(const bf16x8*)(bs + bW + boff[nj][ks]);
        } else if (q == 1) {           // b1 <- B-half1 (a stays mh=0)
            #pragma unroll
            for (int nj = 0; nj < 2; nj++)
                #pragma unroll
                for (int ks = 0; ks < 2; ks++)
                    b1[nj][ks] = *(const bf16x8*)(bs + 128 * BK + bW + boff[nj][ks]);
        } else if (q == 2) {           // a <- A-half1 (b1 stays)
            #pragma unroll
            for (int mi = 0; mi < 4; mi++)
                #pragma unroll
                for (int ks = 0; ks < 2; ks++)
                    a[mi][ks] = *(const bf16x8*)(as + 128 * BK + aW + aoff[mi][ks]);
        }                              // q==3: zero reads (uses a(mh1), b0)

        WAITLG0();
        __builtin_amdgcn_sched_barrier(0);

        const int mh = q >> 1;
        const int nh = (q == 1 || q == 2) ? 1 : 0;
        __builtin_amdgcn_s_setprio(1);
        #pragma unroll
        for (int mi = 0; mi < 4; mi++)
            #pragma unroll
            for (int nj = 0; nj < 2; nj++)
                #pragma unroll
                for (int ks = 0; ks < 2; ks++)
                    acc[mh][mi][nh][nj] = __builtin_amdgcn_mfma_f32_16x16x32_bf16(
                        a[mi][ks], (nh ? b1 : b0)[nj][ks], acc[mh][mi][nh][nj], 0, 0, 0);
        __builtin_amdgcn_s_setprio(0);
        BARRIER();
    }
    #undef STAGE

    // ---- fused ArcFace epilogue ----
    // D layout: row (M) = (lane>>4)*4 + reg, col (N) = lane&15.
    // phi path only where label==cls (rare) -> branch; nontemporal stores.
    const int mrow = (lane >> 4) * 4;
    const int ncol = lane & 15;

    #pragma unroll
    for (int mh = 0; mh < 2; mh++)
        #pragma unroll
        for (int mi = 0; mi < 4; mi++)
            #pragma unroll
            for (int r = 0; r < 4; r++) {
                const int ml  = wr * 64 + mh * 128 + mi * 16 + mrow + r;
                const int lab = sLab[ml];
                float* orow = out + (long long)(m0 + ml) * C_CLS;
                #pragma unroll
                for (int nh = 0; nh < 2; nh++)
                    #pragma unroll
                    for (int nj = 0; nj < 2; nj++) {
                        const int cls = n0 + wc * 32 + nh * 128 + nj * 16 + ncol;
                        if (cls < C_CLS) {
                            float c = fminf(fmaxf(acc[mh][mi][nh][nj][r], -1.0f), 1.0f);
                            float o = c * ARC_S;
                            if (lab == cls) {
                                float tt  = fminf(fmaxf(1.0f - c * c, 1e-9f), 1.0f);
                                float s   = sqrtf(tt);
                                float phi = c * ARC_COSM - s * ARC_SINM;
                                phi = (c > ARC_TH) ? phi : (c - ARC_MM);
                                o = phi * ARC_S;
                            }
                            __builtin_nontemporal_store(o, &orow[cls]);
                        }
                    }
            }
}

// ---------------------------------------------------------------------------
extern "C" void kernel_launch(void* const* d_in, const int* in_sizes, int n_in,
                              void* d_out, int out_size, void* d_ws, size_t ws_size,
                              hipStream_t stream)
{
    const float* inp    = (const float*)d_in[0];
    const int*   label  = (const int*)d_in[1];
    const float* weight = (const float*)d_in[2];
    float*       out    = (float*)d_out;

    // workspace layout: A_bf16 [512*512], W_bf16 [C_PAD*512]
    __bf16* A = (__bf16*)d_ws;
    __bf16* W = A + (size_t)B_ROWS * D_DIM;

    // K1: normalize input rows (512 rows, 4 rows/block)
    normalize_rows_512<<<B_ROWS / 4, 256, 0, stream>>>(inp, A, B_ROWS);
    // K2: normalize weight rows (+ zero-fill padding to C_PAD)
    normalize_rows_512<<<C_PAD / 4, 256, 0, stream>>>(weight, W, C_CLS);
    // K3: GEMM + ArcFace epilogue (8-phase 256x256 template)
    gemm_arcface<<<GRID_B, 512, 0, stream>>>(A, W, label, out);
}